// Round 1
// baseline (4168.798 us; speedup 1.0000x reference)
//
#include <hip/hip_runtime.h>
#include <math.h>

#define BATCH 8
#define SEQ   2048
#define IN    8
#define HID   256
#define G4    1024   // 4*HID

typedef unsigned long long u64;
typedef unsigned int u32;
typedef _Float16 f16;

// ---------------------------------------------------------------------------
// R10 structural rewrite: the 4000cy/step cost of the old 96-block design was
// the per-step cross-XCD LLC pub/poll round trip (R3-R9 exchange tweaks all
// neutral because the latency is structural). Fix: make each (batch, stage)
// fit ONE CU so the recurrence exchange is LDS-only. Only possible with f16
// weights (512KB = 192 VGPRs/thread + 128KB LDS); v_dot2_f32_f16 keeps f32
// accumulation, and c / gate-addends / xp stay f32. Cross-stage streams keep
// the proven tagged-u64 pattern, but with 1-2 step lookahead so LLC latency
// sets pipeline offset, not step rate.
// ---------------------------------------------------------------------------

__device__ __forceinline__ float sigmoidf_(float x) { return 1.0f / (1.0f + __expf(-x)); }
__device__ __forceinline__ float tanhf_(float x) { return 1.0f - 2.0f / (__expf(2.0f * x) + 1.0f); }

// f32 -> packed 2xf16, round-to-nearest-even (NOT cvt_pkrtz: RTZ bias would
// accumulate over 2048 steps).
__device__ __forceinline__ u32 pk2h(float a, float b) {
    unsigned short ua = __builtin_bit_cast(unsigned short, (f16)a);
    unsigned short ub = __builtin_bit_cast(unsigned short, (f16)b);
    return (u32)ua | ((u32)ub << 16);
}
__device__ __forceinline__ float lo16f(u32 v) { return (float)__builtin_bit_cast(f16, (unsigned short)(v & 0xffffu)); }
__device__ __forceinline__ float hi16f(u32 v) { return (float)__builtin_bit_cast(f16, (unsigned short)(v >> 16)); }

__device__ __forceinline__ void light_barrier() {
    __asm__ volatile("s_waitcnt lgkmcnt(0)\n\ts_barrier" ::: "memory");
}

// Tagged u64 {tag<<32 | payload}: payload inside the atomic word -> RELAXED
// agent-scope ops, no fences (proven pattern from the previous session).
__device__ __forceinline__ u64 ld_rlx(const u64* p) {
    return __hip_atomic_load(p, __ATOMIC_RELAXED, __HIP_MEMORY_SCOPE_AGENT);
}
__device__ __forceinline__ void st_rlx(u64* p, u64 v) {
    __hip_atomic_store(p, v, __ATOMIC_RELAXED, __HIP_MEMORY_SCOPE_AGENT);
}
__device__ __forceinline__ void pub_u32(u64* p, u32 tag, u32 pay) { st_rlx(p, ((u64)tag << 32) | (u64)pay); }
__device__ __forceinline__ void pub_f32(u64* p, u32 tag, float x) { pub_u32(p, tag, __float_as_uint(x)); }
// spin until tag matches; v0 is a previously-issued (overlapped) load of *p.
__device__ __forceinline__ u32 spin_u32(const u64* p, u32 tag, u64 v0) {
    u64 v = v0;
    while ((u32)(v >> 32) != tag) v = ld_rlx(p);
    return (u32)v;
}

// keep converted weights live in VGPRs across the step loop (cannot be
// rematerialized through a volatile asm).
__device__ __forceinline__ void pin4(uint4& v) {
    __asm__ volatile("" : "+v"(v.x), "+v"(v.y), "+v"(v.z), "+v"(v.w));
}

// one packed-f16 dot2 with f32 accumulator (full-rate VALU, 2 FMA/instr)
#define DOT2(ACC, W, H) __asm__("v_dot2_f32_f16 %0, %1, %2, %0" : "+v"(ACC) : "v"(W), "v"(H))

// ---------------------------------------------------------------------------
// Per-thread matvec: rows r0,r1 x 256 cols. Cols 0..191 from 48 pinned uint4
// (192 VGPRs), cols 192..255 from LDS (chunk-major layout: addr=(cb*1024+row)*16
// -> consecutive lanes read consecutive 16B, conflict-free). h is 128 packed
// pairs in LDS, read as 32 broadcast b128 loads. 4 accumulator chains/thread
// give 8-way ILP per SIMD at 2 waves/SIMD.
// ---------------------------------------------------------------------------
__device__ __forceinline__ void mv256(const uint4 (&wA)[24], const uint4 (&wB)[24],
                                      const u32* hp, const char* wl,
                                      int r0, int r1, float& o0, float& o1)
{
    float a0 = 0.f, a1 = 0.f, b0 = 0.f, b1 = 0.f;
#pragma unroll
    for (int c = 0; c < 24; c++) {
        const uint4 h4 = *(const uint4*)(hp + c * 4);
        if ((c & 1) == 0) {
            DOT2(a0, wA[c].x, h4.x); DOT2(a0, wA[c].y, h4.y);
            DOT2(a0, wA[c].z, h4.z); DOT2(a0, wA[c].w, h4.w);
            DOT2(a1, wB[c].x, h4.x); DOT2(a1, wB[c].y, h4.y);
            DOT2(a1, wB[c].z, h4.z); DOT2(a1, wB[c].w, h4.w);
        } else {
            DOT2(b0, wA[c].x, h4.x); DOT2(b0, wA[c].y, h4.y);
            DOT2(b0, wA[c].z, h4.z); DOT2(b0, wA[c].w, h4.w);
            DOT2(b1, wB[c].x, h4.x); DOT2(b1, wB[c].y, h4.y);
            DOT2(b1, wB[c].z, h4.z); DOT2(b1, wB[c].w, h4.w);
        }
    }
#pragma unroll
    for (int cb = 0; cb < 8; cb++) {
        const uint4 h4 = *(const uint4*)(hp + (24 + cb) * 4);
        const uint4 wa = *(const uint4*)(wl + (size_t)(((cb << 10) + r0) << 4));
        const uint4 wb = *(const uint4*)(wl + (size_t)(((cb << 10) + r1) << 4));
        if ((cb & 1) == 0) {
            DOT2(a0, wa.x, h4.x); DOT2(a0, wa.y, h4.y);
            DOT2(a0, wa.z, h4.z); DOT2(a0, wa.w, h4.w);
            DOT2(a1, wb.x, h4.x); DOT2(a1, wb.y, h4.y);
            DOT2(a1, wb.z, h4.z); DOT2(a1, wb.w, h4.w);
        } else {
            DOT2(b0, wa.x, h4.x); DOT2(b0, wa.y, h4.y);
            DOT2(b0, wa.z, h4.z); DOT2(b0, wa.w, h4.w);
            DOT2(b1, wb.x, h4.x); DOT2(b1, wb.y, h4.y);
            DOT2(b1, wb.z, h4.z); DOT2(b1, wb.w, h4.w);
        }
    }
    o0 = (a0 + b0); o1 = (a1 + b1);
}

// Load + convert one weight matrix [1024][256] f32 -> f16: cols 0..191 into
// pinned VGPRs, cols 192..255 into LDS (chunk-major).
__device__ __forceinline__ void load_w(const float* __restrict__ Wm, int r0, int r1,
                                       uint4 (&wA)[24], uint4 (&wB)[24], char* wl)
{
#pragma unroll
    for (int c = 0; c < 24; c++) {
        const float4 f0 = *(const float4*)(Wm + (size_t)r0 * HID + c * 8);
        const float4 f1 = *(const float4*)(Wm + (size_t)r0 * HID + c * 8 + 4);
        wA[c] = make_uint4(pk2h(f0.x, f0.y), pk2h(f0.z, f0.w), pk2h(f1.x, f1.y), pk2h(f1.z, f1.w));
        const float4 g0 = *(const float4*)(Wm + (size_t)r1 * HID + c * 8);
        const float4 g1 = *(const float4*)(Wm + (size_t)r1 * HID + c * 8 + 4);
        wB[c] = make_uint4(pk2h(g0.x, g0.y), pk2h(g0.z, g0.w), pk2h(g1.x, g1.y), pk2h(g1.z, g1.w));
        pin4(wA[c]); pin4(wB[c]);
    }
#pragma unroll
    for (int cb = 0; cb < 8; cb++) {
        const float4 f0 = *(const float4*)(Wm + (size_t)r0 * HID + 192 + cb * 8);
        const float4 f1 = *(const float4*)(Wm + (size_t)r0 * HID + 192 + cb * 8 + 4);
        *(uint4*)(wl + (size_t)(((cb << 10) + r0) << 4)) =
            make_uint4(pk2h(f0.x, f0.y), pk2h(f0.z, f0.w), pk2h(f1.x, f1.y), pk2h(f1.z, f1.w));
        const float4 g0 = *(const float4*)(Wm + (size_t)r1 * HID + 192 + cb * 8);
        const float4 g1 = *(const float4*)(Wm + (size_t)r1 * HID + 192 + cb * 8 + 4);
        *(uint4*)(wl + (size_t)(((cb << 10) + r1) << 4)) =
            make_uint4(pk2h(g0.x, g0.y), pk2h(g0.z, g0.w), pk2h(g1.x, g1.y), pk2h(g1.z, g1.w));
    }
}

// ---------------------------------------------------------------------------
// Precompute layer-0 input projection (K=8) + both biases, packed f16 pairs:
// xp16[b][s][p] = pack(row p, row p+512). Pair (t, t+512) == thread t's two
// gate rows in the fused kernel -> one u32 load/thread/step there.
// ---------------------------------------------------------------------------
__global__ __launch_bounds__(256) void xproj_kernel(
    const float* __restrict__ x, const float* __restrict__ w_ih0,
    const float* __restrict__ b_ih0, const float* __restrict__ b_hh0,
    u32* __restrict__ xp16)
{
    const int blk = blockIdx.x;
    const int b = blk >> 7;
    const int s0 = (blk & 127) << 4;
    const int t = threadIdx.x;
    __shared__ float xs[16][8];
    if (t < 128) xs[t >> 3][t & 7] = x[((size_t)b * SEQ + s0 + (t >> 3)) * IN + (t & 7)];
    float w0[8], w1[8], w2[8], w3[8];
#pragma unroll
    for (int k = 0; k < 8; k++) {
        w0[k] = w_ih0[(size_t)(t)       * IN + k];
        w1[k] = w_ih0[(size_t)(t + 512) * IN + k];
        w2[k] = w_ih0[(size_t)(t + 256) * IN + k];
        w3[k] = w_ih0[(size_t)(t + 768) * IN + k];
    }
    const float z0 = b_ih0[t]       + b_hh0[t];
    const float z1 = b_ih0[t + 512] + b_hh0[t + 512];
    const float z2 = b_ih0[t + 256] + b_hh0[t + 256];
    const float z3 = b_ih0[t + 768] + b_hh0[t + 768];
    __syncthreads();
#pragma unroll
    for (int si = 0; si < 16; si++) {
        float d0 = z0, d1 = z1, d2 = z2, d3 = z3;
#pragma unroll
        for (int k = 0; k < 8; k++) {
            const float xk = xs[si][k];
            d0 += w0[k] * xk; d1 += w1[k] * xk; d2 += w2[k] * xk; d3 += w3[k] * xk;
        }
        u32* o = xp16 + ((size_t)b * SEQ + s0 + si) * 512;
        o[t]       = pk2h(d0, d1);
        o[t + 256] = pk2h(d2, d3);
    }
}

// ---------------------------------------------------------------------------
// Fused 2-layer LSTM, one CU per (batch, stage). Grid = 24:
//   bid&7 = batch, bid>>3 = stage: 0=L0 recurrence, 1=P (w_ih1@h0), 2=L1.
// Thread t owns gate rows (t, t+512): t<256 -> (i_u, g_u); t>=256 -> (f_u, o_u).
// Recurrence h-exchange is LDS-only (2 barriers/step). Streams: h0 -> 32-deep
// packed ring; xp -> 32-deep f32 ring; every-8-step progress words for
// backpressure (MAGIC-tagged, poison-proof, reset at prologue).
// ---------------------------------------------------------------------------
__global__ __launch_bounds__(512, 2) void lstm_fused(
    const u32* __restrict__ xp16,
    const float* __restrict__ w_hh0,
    const float* __restrict__ w_ih1, const float* __restrict__ b_ih1, const float* __restrict__ b_hh1,
    const float* __restrict__ w_hh1,
    u64* __restrict__ h0r, u64* __restrict__ xpr, u64* __restrict__ progs,
    float* __restrict__ hbuf)
{
    extern __shared__ char smem[];
    char* wl = smem;                       // [0, 131072): f16 weight cols 192..255
    const int bid = blockIdx.x;
    const int b = bid & 7, stage = bid >> 3;
    const int t = threadIdx.x;
    const int r0 = t, r1 = t + 512;
    const u32 MHI = 0x4C50524Fu;

    u64* h0rb = h0r + (size_t)b * 32 * 128;
    u64* xpb  = xpr + (size_t)b * 32 * G4;

    // progress resets FIRST (before the slow weight load) so readers' first
    // checks (~20us in) can never see a stale value from a previous run.
    if (stage == 1 && t == 0) st_rlx(&progs[8 + b], (u64)MHI << 32);
    if (stage == 2 && t == 0) st_rlx(&progs[b],     (u64)MHI << 32);

    uint4 wA[24], wB[24];
    const float* Wm = (stage == 0) ? w_hh0 : (stage == 1) ? w_ih1 : w_hh1;
    load_w(Wm, r0, r1, wA, wB, wl);

    if (stage == 0) {
        // ================= L0: full layer-0 recurrence on one CU ===========
        u32* hpk   = (u32*)(smem + 131072);           // [2][128] packed h
        float2* fo = (float2*)(smem + 131072 + 1024); // f/o pre-act exchange
        if (t < 256) hpk[t] = 0u;
        const u32* xpp = xp16 + (size_t)b * SEQ * 512 + t;
        u32 xv = xpp[0];
        u32 xn = xpp[512];
        float c = 0.f;
        __syncthreads();
        for (int s = 0; s < SEQ; s++) {
            const int cur = s & 1;
            float o0, o1;
            mv256(wA, wB, hpk + cur * 128, wl, r0, r1, o0, o1);
            if (t >= 256) fo[t - 256] = make_float2(o0 + lo16f(xv), o1 + hi16f(xv));
            light_barrier();
            if (t < 256) {
                const float iv = sigmoidf_(o0 + lo16f(xv));
                const float gv = tanhf_(o1 + hi16f(xv));
                const float2 fov = fo[t];
                const float fv = sigmoidf_(fov.x);
                const float ov = sigmoidf_(fov.y);
                c = fv * c + iv * gv;
                const float hv = ov * tanhf_(c);
                const int nb = __builtin_amdgcn_update_dpp(0, __float_as_int(hv), 0xB1, 0xF, 0xF, false);
                if ((t & 1) == 0) {
                    const u32 pk = pk2h(hv, __int_as_float(nb));
                    hpk[(cur ^ 1) * 128 + (t >> 1)] = pk;
                    pub_u32(&h0rb[(size_t)(s & 31) * 128 + (t >> 1)], (u32)(s + 1), pk);
                }
            }
            xv = xn;
            if (s + 2 < SEQ) xn = xpp[(size_t)(s + 2) * 512];
            if (t == 0 && ((s + 1) & 7) == 0 && s >= 23) {   // gate slots s+1..s+8 vs P
                u64 v; do { v = ld_rlx(&progs[8 + b]); }
                while (!((u32)(v >> 32) == MHI && (u32)v >= (u32)(s - 23)));
            }
            light_barrier();
        }
    } else if (stage == 1) {
        // ================= P: xp[s] = w_ih1 @ h0[s] + biases ===============
        u32* ring = (u32*)(smem + 131072);            // [8][128] packed h0
        const float bs0 = b_ih1[r0] + b_hh1[r0];
        const float bs1 = b_ih1[r1] + b_hh1[r1];
        if (t < 128) {                                // prefill h0[0], h0[1]
            ring[t]       = spin_u32(&h0rb[t],       1u, ld_rlx(&h0rb[t]));
            ring[128 + t] = spin_u32(&h0rb[128 + t], 2u, ld_rlx(&h0rb[128 + t]));
        }
        u64 pend = 0;
        if (t < 128) pend = ld_rlx(&h0rb[(size_t)2 * 128 + t]);
        __syncthreads();
        for (int s = 0; s < SEQ; s++) {
            float o0, o1;
            mv256(wA, wB, ring + (s & 7) * 128, wl, r0, r1, o0, o1);
            // check overlapped poll (h0[s+2]) BEFORE issuing this step's stores
            u32 hv2 = 0;
            if (t < 128 && s + 2 < SEQ)
                hv2 = spin_u32(&h0rb[(size_t)((s + 2) & 31) * 128 + t], (u32)(s + 3), pend);
            pub_f32(&xpb[(size_t)(s & 31) * G4 + r0], (u32)(s + 1), o0 + bs0);
            pub_f32(&xpb[(size_t)(s & 31) * G4 + r1], (u32)(s + 1), o1 + bs1);
            if (t < 128 && s + 2 < SEQ) {
                ring[((s + 2) & 7) * 128 + t] = hv2;
                if (s + 3 < SEQ) pend = ld_rlx(&h0rb[(size_t)((s + 3) & 31) * 128 + t]);
            }
            if (t == 0 && (s & 7) == 7)
                st_rlx(&progs[8 + b], ((u64)MHI << 32) | (u64)(u32)(s + 1));
            if (t == 0 && ((s + 1) & 7) == 0 && s >= 23) {   // gate xpr slots vs L1
                u64 v; do { v = ld_rlx(&progs[b]); }
                while (!((u32)(v >> 32) == MHI && (u32)v >= (u32)(s - 23)));
            }
            light_barrier();
        }
    } else {
        // ================= L1: full layer-1 recurrence on one CU ===========
        u32* hpk   = (u32*)(smem + 131072);
        float2* fo = (float2*)(smem + 131072 + 1024);
        float* ho = hbuf + (size_t)b * SEQ * HID;
        if (t < 256) hpk[t] = 0u;
        float xv0 = __uint_as_float(spin_u32(&xpb[r0], 1u, ld_rlx(&xpb[r0])));
        float xv1 = __uint_as_float(spin_u32(&xpb[r1], 1u, ld_rlx(&xpb[r1])));
        u64 p0 = ld_rlx(&xpb[(size_t)1 * G4 + r0]);
        u64 p1 = ld_rlx(&xpb[(size_t)1 * G4 + r1]);
        float c = 0.f;
        __syncthreads();
        for (int s = 0; s < SEQ; s++) {
            const int cur = s & 1;
            float o0, o1;
            mv256(wA, wB, hpk + cur * 128, wl, r0, r1, o0, o1);
            float xn0 = 0.f, xn1 = 0.f;
            if (s + 1 < SEQ) {   // check overlapped polls (xp[s+1]) before stores
                xn0 = __uint_as_float(spin_u32(&xpb[(size_t)((s + 1) & 31) * G4 + r0], (u32)(s + 2), p0));
                xn1 = __uint_as_float(spin_u32(&xpb[(size_t)((s + 1) & 31) * G4 + r1], (u32)(s + 2), p1));
            }
            if (t >= 256) fo[t - 256] = make_float2(o0 + xv0, o1 + xv1);
            light_barrier();
            if (t < 256) {
                const float iv = sigmoidf_(o0 + xv0);
                const float gv = tanhf_(o1 + xv1);
                const float2 fov = fo[t];
                const float fv = sigmoidf_(fov.x);
                const float ov = sigmoidf_(fov.y);
                c = fv * c + iv * gv;
                const float hv = ov * tanhf_(c);
                ho[(size_t)s * HID + t] = hv;
                const int nb = __builtin_amdgcn_update_dpp(0, __float_as_int(hv), 0xB1, 0xF, 0xF, false);
                if ((t & 1) == 0)
                    hpk[(cur ^ 1) * 128 + (t >> 1)] = pk2h(hv, __int_as_float(nb));
            }
            xv0 = xn0; xv1 = xn1;
            if (s + 2 < SEQ) {
                p0 = ld_rlx(&xpb[(size_t)((s + 2) & 31) * G4 + r0]);
                p1 = ld_rlx(&xpb[(size_t)((s + 2) & 31) * G4 + r1]);
            }
            if (t == 0 && (s & 7) == 7)
                st_rlx(&progs[b], ((u64)MHI << 32) | (u64)(u32)(s + 1));
            light_barrier();
        }
    }
}

// ---------------------------------------------------------------------------
// K and V projections in one launch (blockIdx.z selects). NT GEMM,
// 128x128x16 tiles, 256 threads, 8x8 micro-tile. (unchanged)
// ---------------------------------------------------------------------------
__global__ __launch_bounds__(256) void gemm_kv(
    const float* __restrict__ A,
    const float* __restrict__ Wk, const float* __restrict__ bk,
    const float* __restrict__ Wv, const float* __restrict__ bv,
    float* __restrict__ Ck, float* __restrict__ Cv, int M, int N, int K)
{
    const float* W    = blockIdx.z ? Wv : Wk;
    const float* bias = blockIdx.z ? bv : bk;
    float*       C    = blockIdx.z ? Cv : Ck;

    __shared__ float As[16][132];
    __shared__ float Bs[16][132];
    const int tid = threadIdx.x;
    const int tx = tid & 15;
    const int ty = tid >> 4;
    const int bm = blockIdx.x * 128;
    const int bn = blockIdx.y * 128;
    const int lrow = tid >> 1;
    const int lk = (tid & 1) * 8;

    float acc[8][8] = {};

    for (int k0 = 0; k0 < K; k0 += 16) {
        const float* ap = A + (size_t)(bm + lrow) * K + k0 + lk;
        const float* wp = W + (size_t)(bn + lrow) * K + k0 + lk;
        const float4 a0 = *(const float4*)ap;
        const float4 a1 = *(const float4*)(ap + 4);
        const float4 w0 = *(const float4*)wp;
        const float4 w1 = *(const float4*)(wp + 4);
        __syncthreads();
        As[lk+0][lrow] = a0.x; As[lk+1][lrow] = a0.y; As[lk+2][lrow] = a0.z; As[lk+3][lrow] = a0.w;
        As[lk+4][lrow] = a1.x; As[lk+5][lrow] = a1.y; As[lk+6][lrow] = a1.z; As[lk+7][lrow] = a1.w;
        Bs[lk+0][lrow] = w0.x; Bs[lk+1][lrow] = w0.y; Bs[lk+2][lrow] = w0.z; Bs[lk+3][lrow] = w0.w;
        Bs[lk+4][lrow] = w1.x; Bs[lk+5][lrow] = w1.y; Bs[lk+6][lrow] = w1.z; Bs[lk+7][lrow] = w1.w;
        __syncthreads();
#pragma unroll
        for (int k = 0; k < 16; k++) {
            const float4 av0 = *(const float4*)(&As[k][ty * 4]);
            const float4 av1 = *(const float4*)(&As[k][64 + ty * 4]);
            const float4 bv0 = *(const float4*)(&Bs[k][tx * 4]);
            const float4 bv1 = *(const float4*)(&Bs[k][64 + tx * 4]);
            const float ar[8] = {av0.x, av0.y, av0.z, av0.w, av1.x, av1.y, av1.z, av1.w};
            const float br[8] = {bv0.x, bv0.y, bv0.z, bv0.w, bv1.x, bv1.y, bv1.z, bv1.w};
#pragma unroll
            for (int i = 0; i < 8; i++)
#pragma unroll
                for (int j = 0; j < 8; j++) acc[i][j] += ar[i] * br[j];
        }
    }

    const int c0 = bn + tx * 4, c1 = bn + 64 + tx * 4;
    const float4 bb0 = *(const float4*)(bias + c0);
    const float4 bb1 = *(const float4*)(bias + c1);
#pragma unroll
    for (int ih = 0; ih < 2; ih++)
#pragma unroll
        for (int i = 0; i < 4; i++) {
            const int row = bm + ih * 64 + ty * 4 + i;
            const int ai = ih * 4 + i;
            float4 o0, o1;
            o0.x = acc[ai][0] + bb0.x; o0.y = acc[ai][1] + bb0.y;
            o0.z = acc[ai][2] + bb0.z; o0.w = acc[ai][3] + bb0.w;
            o1.x = acc[ai][4] + bb1.x; o1.y = acc[ai][5] + bb1.y;
            o1.z = acc[ai][6] + bb1.z; o1.w = acc[ai][7] + bb1.w;
            *(float4*)(C + (size_t)row * N + c0) = o0;
            *(float4*)(C + (size_t)row * N + c1) = o1;
        }
}

// ---------------------------------------------------------------------------
// Q projection at the last position only. (unchanged)
// ---------------------------------------------------------------------------
__global__ __launch_bounds__(256) void qlast_kernel(
    const float* __restrict__ h1, const float* __restrict__ wq,
    const float* __restrict__ bq, float* __restrict__ qout)
{
    const int b = blockIdx.x;
    const int t = threadIdx.x;
    __shared__ __align__(16) float hs[HID];
    hs[t] = h1[((size_t)b * SEQ + (SEQ - 1)) * HID + t];
    __syncthreads();
    const float4* wr = (const float4*)(wq + (size_t)t * HID);
    float acc = 0.0f;
#pragma unroll
    for (int k = 0; k < 64; k++) {
        const float4 wv = wr[k];
        const float4 hv = ((const float4*)hs)[k];
        acc += wv.x*hv.x + wv.y*hv.y + wv.z*hv.z + wv.w*hv.w;
    }
    qout[b * HID + t] = acc + bq[t];
}

// ---------------------------------------------------------------------------
// Decode attention at query S-1 with multiplicative decay on scores. (unchanged)
// ---------------------------------------------------------------------------
__global__ __launch_bounds__(256) void attn_kernel(
    const float* __restrict__ Kb, const float* __restrict__ Vb,
    const float* __restrict__ q, float* __restrict__ attn)
{
    const int b = blockIdx.x >> 2;
    const int h = blockIdx.x & 3;
    const int tid = threadIdx.x;

    __shared__ __align__(16) float qs[64];
    __shared__ float sc[SEQ];
    __shared__ float red[256];
    __shared__ float part[4][64];

    if (tid < 64) qs[tid] = q[b * HID + h * 64 + tid];
    __syncthreads();

    const float LN095 = -0.051293294387550533f;  // ln(0.95)
    for (int k = tid; k < SEQ; k += 256) {
        const float4* kr = (const float4*)(Kb + ((size_t)b * SEQ + k) * HID + h * 64);
        float acc = 0.0f;
#pragma unroll
        for (int d = 0; d < 16; d++) {
            const float4 kv = kr[d];
            const float4 qv = ((const float4*)qs)[d];
            acc += kv.x*qv.x + kv.y*qv.y + kv.z*qv.z + kv.w*qv.w;
        }
        const float dec = __expf(LN095 * (float)(SEQ - 1 - k));
        sc[k] = acc * 0.125f * dec;
    }
    __syncthreads();

    float m = -INFINITY;
    for (int k = tid; k < SEQ; k += 256) m = fmaxf(m, sc[k]);
    red[tid] = m;
    for (int off = 128; off > 0; off >>= 1) {
        __syncthreads();
        if (tid < off) red[tid] = fmaxf(red[tid], red[tid + off]);
    }
    __syncthreads();
    const float mx = red[0];

    float local = 0.0f;
    for (int k = tid; k < SEQ; k += 256) {
        const float p = expf(sc[k] - mx);
        sc[k] = p;
        local += p;
    }
    __syncthreads();
    red[tid] = local;
    for (int off = 128; off > 0; off >>= 1) {
        __syncthreads();
        if (tid < off) red[tid] += red[tid + off];
    }
    __syncthreads();
    const float total = red[0];

    const int chunk = tid >> 6;
    const int d = tid & 63;
    float acc = 0.0f;
    const int k0 = chunk * (SEQ / 4), k1 = (chunk + 1) * (SEQ / 4);
    for (int k = k0; k < k1; k++)
        acc += sc[k] * Vb[((size_t)b * SEQ + k) * HID + h * 64 + d];
    part[chunk][d] = acc;
    __syncthreads();
    if (tid < 64) {
        const float r = (part[0][tid] + part[1][tid]) + (part[2][tid] + part[3][tid]);
        attn[b * HID + h * 64 + tid] = r / total;
    }
}

// ---------------------------------------------------------------------------
// Head: context = attn @ wo^T + bo ; mean/log_var heads (5 each). (unchanged)
// ---------------------------------------------------------------------------
__global__ __launch_bounds__(256) void head_kernel(
    const float* __restrict__ attn, const float* __restrict__ wo,
    const float* __restrict__ bo, const float* __restrict__ w_mean,
    const float* __restrict__ b_mean, const float* __restrict__ w_var,
    const float* __restrict__ b_var, float* __restrict__ out)
{
    const int b = blockIdx.x;
    const int t = threadIdx.x;
    __shared__ __align__(16) float av[HID];
    __shared__ __align__(16) float ctx[HID];
    av[t] = attn[b * HID + t];
    __syncthreads();
    {
        const float4* wr = (const float4*)(wo + (size_t)t * HID);
        float acc = 0.0f;
#pragma unroll
        for (int k = 0; k < 64; k++) {
            const float4 wv = wr[k];
            const float4 hv = ((const float4*)av)[k];
            acc += wv.x*hv.x + wv.y*hv.y + wv.z*hv.z + wv.w*hv.w;
        }
        ctx[t] = acc + bo[t];
    }
    __syncthreads();
    if (t < 5) {
        const float4* wr = (const float4*)(w_mean + (size_t)t * HID);
        float acc = 0.0f;
#pragma unroll
        for (int k = 0; k < 64; k++) {
            const float4 wv = wr[k];
            const float4 hv = ((const float4*)ctx)[k];
            acc += wv.x*hv.x + wv.y*hv.y + wv.z*hv.z + wv.w*hv.w;
        }
        out[b * 5 + t] = acc + b_mean[t];
    } else if (t >= 8 && t < 13) {
        const int m = t - 8;
        const float4* wr = (const float4*)(w_var + (size_t)m * HID);
        float acc = 0.0f;
#pragma unroll
        for (int k = 0; k < 64; k++) {
            const float4 wv = wr[k];
            const float4 hv = ((const float4*)ctx)[k];
            acc += wv.x*hv.x + wv.y*hv.y + wv.z*hv.z + wv.w*hv.w;
        }
        out[BATCH * 5 + b * 5 + m] = acc + b_var[m];
    }
}

// ---------------------------------------------------------------------------
extern "C" void kernel_launch(void* const* d_in, const int* in_sizes, int n_in,
                              void* d_out, int out_size, void* d_ws, size_t ws_size,
                              hipStream_t stream) {
    const float* x      = (const float*)d_in[0];
    const float* w_ih0  = (const float*)d_in[1];
    const float* w_hh0  = (const float*)d_in[2];
    const float* b_ih0  = (const float*)d_in[3];
    const float* b_hh0  = (const float*)d_in[4];
    const float* w_ih1  = (const float*)d_in[5];
    const float* w_hh1  = (const float*)d_in[6];
    const float* b_ih1  = (const float*)d_in[7];
    const float* b_hh1  = (const float*)d_in[8];
    const float* wq     = (const float*)d_in[9];
    const float* bq     = (const float*)d_in[10];
    const float* wk     = (const float*)d_in[11];
    const float* bk     = (const float*)d_in[12];
    const float* wvv    = (const float*)d_in[13];
    const float* bv     = (const float*)d_in[14];
    const float* wo     = (const float*)d_in[15];
    const float* bo     = (const float*)d_in[16];
    const float* w_mean = (const float*)d_in[17];
    const float* b_mean = (const float*)d_in[18];
    const float* w_var  = (const float*)d_in[19];
    const float* b_var  = (const float*)d_in[20];
    float* out = (float*)d_out;

    // ws layout (bytes), ~50.3 MB peak (<= previous session's 52 MB footprint):
    //  [0, 16M)            hbuf  (plain h1; LSTM writes, KV/qlast read)
    //  [16M, 48M)          xp16  (f16-pair layer-0 input proj)  -> Kbuf|Vbuf after
    //  [48M, 48M+256K)     h0r   (32-deep tagged packed-h0 ring) -> qbuf|abuf after
    //  [48M+256K, +2M)     xpr   (32-deep tagged f32 xp ring)
    //  [52690944, +128B)   progs (L1prog[8], Pprog[8])
    char* wsb = (char*)d_ws;
    float* hbuf = (float*)wsb;
    u32*  xp16  = (u32*)(wsb + 16777216);
    u64*  h0r   = (u64*)(wsb + 50331648);
    u64*  xpr   = (u64*)(wsb + 50593792);
    u64*  progs = (u64*)(wsb + 52690944);
    float* Kbuf = (float*)(wsb + 16777216);
    float* Vbuf = (float*)(wsb + 33554432);
    float* qbuf = (float*)(wsb + 50331648);
    float* abuf = (float*)(wsb + 50331648 + 8192);

    static bool attr_done = false;
    if (!attr_done) {
        hipFuncSetAttribute(reinterpret_cast<const void*>(lstm_fused),
                            hipFuncAttributeMaxDynamicSharedMemorySize, 135168);
        attr_done = true;
    }

    // 1. layer-0 input projection (f16 pairs, biases folded)
    xproj_kernel<<<1024, 256, 0, stream>>>(x, w_ih0, b_ih0, b_hh0, xp16);
    // 2. fused single-CU-per-stage pipelined 2-layer LSTM
    lstm_fused<<<24, 512, 135168, stream>>>(xp16, w_hh0, w_ih1, b_ih1, b_hh1, w_hh1,
                                            h0r, xpr, progs, hbuf);
    // 3. K and V projections (one launch)
    gemm_kv<<<dim3(128, 2, 2), 256, 0, stream>>>(hbuf, wk, bk, wvv, bv, Kbuf, Vbuf, 16384, 256, 256);
    // 4. Q at last position
    qlast_kernel<<<BATCH, 256, 0, stream>>>(hbuf, wq, bq, qbuf);
    // 5. decode attention with decay
    attn_kernel<<<BATCH * 4, 256, 0, stream>>>(Kbuf, Vbuf, qbuf, abuf);
    // 6. output proj + gaussian head
    head_kernel<<<BATCH, 256, 0, stream>>>(abuf, wo, bo, w_mean, b_mean, w_var, b_var, out);
}